// Round 11
// baseline (538.583 us; speedup 1.0000x reference)
//
#include <hip/hip_runtime.h>
#include <hip/hip_bf16.h>

#define DD 128

typedef _Float16 h8_t __attribute__((ext_vector_type(8)));
typedef _Float16 h4_t __attribute__((ext_vector_type(4)));
typedef unsigned short us8_t __attribute__((ext_vector_type(8)));
typedef float f4_t __attribute__((ext_vector_type(4)));
typedef unsigned int u32x4 __attribute__((ext_vector_type(4)));
typedef float f32x4 __attribute__((ext_vector_type(4)));
typedef unsigned long long u64;

__device__ inline float bf2f(unsigned short u) {
  union { unsigned int i; float f; } v;
  v.i = ((unsigned int)u) << 16;
  return v.f;
}

__device__ inline float sat(float v) {
  return fminf(fmaxf(v, -60000.f), 60000.f);
}

// dtype-adaptive scalar load: mode 1 = float32 array, mode 0 = bf16 array
__device__ inline float ldf(const void* p, int i, int f32m) {
  return f32m ? ((const float*)p)[i] : bf2f(((const unsigned short*)p)[i]);
}

#define P1_T 4096
#define NBMAX 256
#define P2_CAP 12288  // max records per bucket held in LDS (96KB); overflow -> direct

// shared weight-swizzle body:
// Wt[l][((t*4+kk)*64+lane)*8+j] = W_l[kk*32 + (lane>>4)*8 + j][t*16 + (lane&15)]
__device__ inline void cvt_w_body(const void* __restrict__ W1,
                                  const void* __restrict__ W2,
                                  const void* __restrict__ W3,
                                  _Float16* __restrict__ Wt, int f32m, int i) {
  if (i >= 3 * 16384) return;
  int l = i >> 14, o = i & 16383;
  int j = o & 7, lane = (o >> 3) & 63, kkt = o >> 9;
  int kk = kkt & 3, t = kkt >> 2;
  int k = kk * 32 + (lane >> 4) * 8 + j;
  int n = t * 16 + (lane & 15);
  const void* W = (l == 0) ? W1 : (l == 1 ? W2 : W3);
  Wt[i] = (_Float16)ldf(W, k * 128 + n, f32m);
}

// ---------------- bucket histogram (+ fused dtype-detect in last block) --------
// Persists each block's local histogram (blkhist) so k_p1 can skip its own
// phase-1 row pass entirely.

__global__ __launch_bounds__(256) void k_bhist(const int* __restrict__ row,
                                               int* __restrict__ bcnt, int E, int N,
                                               const unsigned int* __restrict__ nf,
                                               int* __restrict__ flag,
                                               int* __restrict__ blkhist) {
  if (blockIdx.x == gridDim.x - 1) {
    // dtype-detect block (flag=1 -> f32 inputs)
    __shared__ int cnt;
    if (threadIdx.x == 0) cnt = 0;
    __syncthreads();
    int bad = 0;
#pragma unroll
    for (int k = 0; k < 8; ++k) {
      unsigned int w = nf[threadIdx.x * 8 + k];
#pragma unroll
      for (int h = 0; h < 2; ++h) {
        unsigned short us = (h == 0) ? (unsigned short)(w & 0xFFFF)
                                     : (unsigned short)(w >> 16);
        float v = bf2f(us);
        float av = fabsf(v);
        if (!(av <= 1e5f) || (av != 0.f && av < 1e-30f)) bad++;
      }
    }
    atomicAdd(&cnt, bad);
    __syncthreads();
    if (threadIdx.x == 0) *flag = (cnt > 200) ? 1 : 0;
    return;
  }
  __shared__ int hist[NBMAX];
  int tid = threadIdx.x;
  hist[tid] = 0;
  __syncthreads();
  int e0 = blockIdx.x * P1_T;
#pragma unroll
  for (int k = 0; k < P1_T / 256; ++k) {
    int i = e0 + k * 256 + tid;
    if (i < E) {
      int r = row[i];
      if ((unsigned)r < (unsigned)N) atomicAdd(&hist[r >> 9], 1);
    }
  }
  __syncthreads();
  int c = hist[tid];
  blkhist[blockIdx.x * 256 + tid] = c;
  if (c) atomicAdd(&bcnt[tid], c);
}

// single block: scan NB bucket counts -> bucket bases + p1 cursors + offs[N]
__global__ __launch_bounds__(256) void k_bscan(const int* __restrict__ bcnt,
                                               int* __restrict__ bbase,
                                               int* __restrict__ bcur,
                                               int* __restrict__ offs,
                                               int NB, int N) {
  __shared__ int sh[NBMAX + 1];
  int tid = threadIdx.x;
  sh[tid] = (tid < NB) ? bcnt[tid] : 0;
  __syncthreads();
  if (tid == 0) {
    int run = 0;
    for (int i = 0; i < NB; ++i) {
      int t = sh[i];
      sh[i] = run;
      run += t;
    }
    sh[NB] = run;
    offs[N] = run;
  }
  __syncthreads();
  if (tid < NB) {
    bbase[tid] = sh[tid];
    bcur[tid] = sh[tid];
  }
  if (tid == 0) bbase[NB] = sh[NB];
}

// ---------------- bucketed fill pass 1 (+ fused weight swizzle blocks) --------
// Bucket = row>>9 (512 nodes). Requires N < 2^17 (=> NB <= 256, col fits 17 bits).
// Blocks >= p1b perform the weight swizzle (flag ready: detect ran in k_bhist).
// Phase-1 local histogram is read from blkhist (computed by k_bhist).
// stage stores are non-temporal (read once by p2n; keep L2 for live data).

__global__ __launch_bounds__(256) void k_p1(const int* __restrict__ row,
                                            const int* __restrict__ col,
                                            const void* __restrict__ ew,
                                            int* __restrict__ bcur,
                                            u64* __restrict__ stage,
                                            int E, int N, int NB,
                                            const int* __restrict__ flag,
                                            const int* __restrict__ blkhist,
                                            const void* __restrict__ W1,
                                            const void* __restrict__ W2,
                                            const void* __restrict__ W3,
                                            _Float16* __restrict__ Wt, int p1b) {
  int f32m = *flag;
  if (blockIdx.x >= p1b) {
    cvt_w_body(W1, W2, W3, Wt, f32m, (blockIdx.x - p1b) * 256 + threadIdx.x);
    return;
  }
  __shared__ int hist[NBMAX];
  __shared__ int basep[NBMAX];
  int tid = threadIdx.x;
  int e0 = blockIdx.x * P1_T;
  if (tid < NB) {
    int c = blkhist[blockIdx.x * 256 + tid];
    basep[tid] = c ? atomicAdd(&bcur[tid], c) : 0;
    hist[tid] = 0;
  }
  __syncthreads();
#pragma unroll
  for (int k = 0; k < P1_T / 256; ++k) {
    int i = e0 + k * 256 + tid;
    if (i < E) {
      int r = row[i];
      if ((unsigned)r < (unsigned)N) {
        int b = r >> 9;
        int loc = atomicAdd(&hist[b], 1);
        int pos = basep[b] + loc;
        int c = col[i];
        if ((unsigned)c >= (unsigned)N) c = 0;
        unsigned int wb = __float_as_uint(ldf(ew, i, f32m));
        u64 pk = ((u64)wb << 32) | (unsigned int)(c | ((r & 511) << 17));
        __builtin_nontemporal_store(pk, &stage[pos]);
      }
    }
  }
}

// ---------------- pass 2: per-node offsets + record placement ----------------
// rec stores are non-temporal (consumed much later by k_agg).

__global__ __launch_bounds__(256) void k_p2n(const int* __restrict__ bbase,
                                             const u64* __restrict__ stage,
                                             u64* __restrict__ rec,
                                             int* __restrict__ offs, int N) {
  __shared__ int lcnt[512];
  __shared__ int lex[512];
  __shared__ int wsum[4];
  __shared__ u64 recbuf[P2_CAP];
  int b = blockIdx.x;
  int base = b << 9;
  int nend = base + 512;
  if (nend > N) nend = N;
  int nn = nend - base;
  int recbase = bbase[b];
  int cnt = bbase[b + 1] - recbase;
  int tid = threadIdx.x;
  lcnt[tid] = 0;
  lcnt[tid + 256] = 0;
  __syncthreads();
  for (int j = tid; j < cnt; j += 256) {
    unsigned int lo = (unsigned int)stage[recbase + j];
    atomicAdd(&lcnt[(lo >> 17) & 511], 1);
  }
  __syncthreads();
  // exclusive scan of 512 counters (2 per thread, wave scan + wave-sum combine)
  int v0 = lcnt[2 * tid], v1 = lcnt[2 * tid + 1];
  int s = v0 + v1;
  int sc = s;
  int lane = tid & 63, w = tid >> 6;
#pragma unroll
  for (int d = 1; d < 64; d <<= 1) {
    int t = __shfl_up(sc, d, 64);
    if (lane >= d) sc += t;
  }
  if (lane == 63) wsum[w] = sc;
  __syncthreads();
  int wbase = 0;
  for (int x = 0; x < w; ++x) wbase += wsum[x];
  int run = wbase + (sc - s);
  lex[2 * tid] = run;
  lex[2 * tid + 1] = run + v0;
  __syncthreads();
  for (int v = tid; v < nn; v += 256) offs[base + v] = recbase + lex[v];
  // reuse lcnt as placement cursors
  lcnt[tid] = lex[tid];
  lcnt[tid + 256] = lex[tid + 256];
  __syncthreads();
  for (int j = tid; j < cnt; j += 256) {
    u64 pk = stage[recbase + j];
    unsigned int lo = (unsigned int)pk;
    unsigned int wb = (unsigned int)(pk >> 32);
    int c = lo & 0x1FFFF;
    int rloc = (lo >> 17) & 511;
    int pos = atomicAdd(&lcnt[rloc], 1);
    u64 out = ((u64)wb << 32) | (unsigned int)c;  // int2{col, wbits} little-endian
    if (pos < P2_CAP) recbuf[pos] = out;
    else __builtin_nontemporal_store(out, &rec[recbase + pos]);
  }
  __syncthreads();
  int m = cnt < P2_CAP ? cnt : P2_CAP;
  for (int j = tid; j < m; j += 256)
    __builtin_nontemporal_store(recbuf[j], &rec[recbase + j]);
}

// ---------------- fallback chain (N >= 2^17 only) ----------------

__global__ __launch_bounds__(256) void k_hist(const int* __restrict__ row,
                                              int* __restrict__ deg, int E, int N,
                                              const unsigned int* __restrict__ nf,
                                              int* __restrict__ flag) {
  if (blockIdx.x == gridDim.x - 1) {
    __shared__ int cnt;
    if (threadIdx.x == 0) cnt = 0;
    __syncthreads();
    int bad = 0;
#pragma unroll
    for (int k = 0; k < 8; ++k) {
      unsigned int w = nf[threadIdx.x * 8 + k];
#pragma unroll
      for (int h = 0; h < 2; ++h) {
        unsigned short us = (h == 0) ? (unsigned short)(w & 0xFFFF)
                                     : (unsigned short)(w >> 16);
        float v = bf2f(us);
        float av = fabsf(v);
        if (!(av <= 1e5f) || (av != 0.f && av < 1e-30f)) bad++;
      }
    }
    atomicAdd(&cnt, bad);
    __syncthreads();
    if (threadIdx.x == 0) *flag = (cnt > 200) ? 1 : 0;
    return;
  }
  int i = blockIdx.x * 256 + threadIdx.x;
  if (i < E) {
    int r = row[i];
    if ((unsigned)r < (unsigned)N) atomicAdd(&deg[r], 1);
  }
}

__global__ __launch_bounds__(256) void k_scan1(const int* __restrict__ deg,
                                               int* __restrict__ bsum, int n) {
  int i0 = blockIdx.x * 1024 + threadIdx.x * 4;
  int s = 0;
#pragma unroll
  for (int k = 0; k < 4; ++k) {
    int i = i0 + k;
    if (i < n) s += deg[i];
  }
#pragma unroll
  for (int d = 1; d < 64; d <<= 1) s += __shfl_xor(s, d, 64);
  __shared__ int ws[4];
  int lane = threadIdx.x & 63, w = threadIdx.x >> 6;
  if (lane == 0) ws[w] = s;
  __syncthreads();
  if (threadIdx.x == 0) bsum[blockIdx.x] = ws[0] + ws[1] + ws[2] + ws[3];
}

__global__ __launch_bounds__(1024) void k_scan2(int* __restrict__ bsum,
                                                int* __restrict__ offs,
                                                int nb, int n) {
  __shared__ int sh[1024];
  int tid = threadIdx.x;
  sh[tid] = (tid < nb) ? bsum[tid] : 0;
  __syncthreads();
  if (tid == 0) {
    int run = 0;
    for (int i = 0; i < nb; ++i) {
      int t = sh[i];
      sh[i] = run;
      run += t;
    }
    offs[n] = run;
  }
  __syncthreads();
  if (tid < nb) bsum[tid] = sh[tid];
}

__global__ __launch_bounds__(256) void k_scan3(const int* __restrict__ deg,
                                               const int* __restrict__ bsum,
                                               int* __restrict__ offs,
                                               int* __restrict__ cursor, int n) {
  int tid = threadIdx.x, lane = tid & 63, w = tid >> 6;
  int i0 = blockIdx.x * 1024 + tid * 4;
  int v0 = 0, v1 = 0, v2 = 0, v3 = 0;
  if (i0 + 3 < n) {
    v0 = deg[i0]; v1 = deg[i0 + 1]; v2 = deg[i0 + 2]; v3 = deg[i0 + 3];
  } else {
    if (i0 < n) v0 = deg[i0];
    if (i0 + 1 < n) v1 = deg[i0 + 1];
    if (i0 + 2 < n) v2 = deg[i0 + 2];
  }
  int s = v0 + v1 + v2 + v3;
  int sc = s;
#pragma unroll
  for (int d = 1; d < 64; d <<= 1) {
    int t = __shfl_up(sc, d, 64);
    if (lane >= d) sc += t;
  }
  __shared__ int ws[4];
  if (lane == 63) ws[w] = sc;
  __syncthreads();
  int wbase = 0;
  for (int x = 0; x < w; ++x) wbase += ws[x];
  int run = bsum[blockIdx.x] + wbase + (sc - s);
  if (i0 < n)     { offs[i0] = run;     cursor[i0] = run;     run += v0; }
  if (i0 + 1 < n) { offs[i0 + 1] = run; cursor[i0 + 1] = run; run += v1; }
  if (i0 + 2 < n) { offs[i0 + 2] = run; cursor[i0 + 2] = run; run += v2; }
  if (i0 + 3 < n) { offs[i0 + 3] = run; cursor[i0 + 3] = run; }
}

__global__ __launch_bounds__(256) void k_fill(const int* __restrict__ row,
                                              const int* __restrict__ col,
                                              const void* __restrict__ ew,
                                              int* __restrict__ cursor,
                                              int2* __restrict__ rec, int E, int N,
                                              const int* __restrict__ flag) {
  int f32m = *flag;
  int i = blockIdx.x * 256 + threadIdx.x;
  if (i >= E) return;
  int r = row[i];
  if ((unsigned)r >= (unsigned)N) return;
  int p = atomicAdd(&cursor[r], 1);
  if ((unsigned)p >= (unsigned)E) return;
  int c = col[i];
  if ((unsigned)c >= (unsigned)N) c = 0;
  rec[p] = make_int2(c, __float_as_int(ldf(ew, i, f32m)));
}

__global__ __launch_bounds__(256) void k_cvt_w(const void* __restrict__ W1,
                                               const void* __restrict__ W2,
                                               const void* __restrict__ W3,
                                               _Float16* __restrict__ Wt,
                                               const int* __restrict__ flag) {
  cvt_w_body(W1, W2, W3, Wt, *flag, blockIdx.x * 256 + threadIdx.x);
}

// ---------------- BN prep: reduce 64 stat partials -> scale/shift + coeffs ----
// pb layout: [64][256] = {sum[128] | sumsq[128]} per slot
// bn[0..127]=sc, bn[128..255]=sh, bn[256..260]=p0..p4
// NOTE (R9 lesson): do NOT fuse this into k_agg via grid-counter+__threadfence —
// device-scope fences per block flush L2 across XCDs and collapsed agg 82->711us.

__global__ __launch_bounds__(128) void k_bnprep(const float* __restrict__ pb,
                                                const void* __restrict__ gamma,
                                                const void* __restrict__ beta,
                                                const void* __restrict__ coeffs,
                                                int coff, float invN,
                                                float* __restrict__ bn,
                                                const int* __restrict__ flag) {
  int f32m = *flag;
  int c = threadIdx.x;
  float s = 0.f, s2 = 0.f;
#pragma unroll 8
  for (int p = 0; p < 64; ++p) {
    s += pb[p * 256 + c];
    s2 += pb[p * 256 + 128 + c];
  }
  float mn = s * invN;
  float var = fmaf(-mn, mn, s2 * invN);
  var = fmaxf(var, 0.0f);
  float inv = rsqrtf(var + 1e-5f);
  float g = ldf(gamma, c, f32m);
  float scv = g * inv;
  bn[c] = scv;
  bn[128 + c] = ldf(beta, c, f32m) - mn * scv;
  if (c < 5) bn[256 + c] = ldf(coeffs, coff + c, f32m);
}

// ---------------- GEMM (MFMA): H = act(X) @ W ----------------
// MODE 0: X = raw input (f32 or bf16 per flag), no activation (layer 0)
// MODE 1: X = fp16 agg output; apply BN (sc,sh) + 4th-order Horner inline
// A frag: m=lane&15, k=(lane>>4)*8+j.  B pre-swizzled.  C/D: col=m, row=q*4+reg.
// pbz != null: blocks 0..63 zero the stats partial buffer (replaces memset).

template <int MODE>
__global__ __launch_bounds__(256) void k_gemm(const void* __restrict__ Xraw,
                                              const _Float16* __restrict__ Wt,
                                              _Float16* __restrict__ H, int nrows,
                                              const float* __restrict__ bn,
                                              const int* __restrict__ flag,
                                              float* __restrict__ pbz) {
  if (pbz != nullptr && blockIdx.x < 64)
    pbz[(blockIdx.x << 8) + threadIdx.x] = 0.f;
  int gw = (blockIdx.x * 256 + threadIdx.x) >> 6;
  int lane = threadIdx.x & 63;
  int r0 = gw << 4;
  if (r0 >= nrows) return;
  int m = lane & 15, q = lane >> 4;
  int rr = r0 + m;
  if (rr >= nrows) rr = nrows - 1;
  h8_t a[4];
  if (MODE == 0) {
    int f32m = *flag;
    if (f32m) {
      const float* X = (const float*)Xraw + (size_t)rr * DD + q * 8;
#pragma unroll
      for (int kk = 0; kk < 4; ++kk) {
        float4 u0 = *(const float4*)(X + kk * 32);
        float4 u1 = *(const float4*)(X + kk * 32 + 4);
        a[kk] = h8_t{(_Float16)u0.x, (_Float16)u0.y, (_Float16)u0.z, (_Float16)u0.w,
                     (_Float16)u1.x, (_Float16)u1.y, (_Float16)u1.z, (_Float16)u1.w};
      }
    } else {
      const unsigned short* X = (const unsigned short*)Xraw + (size_t)rr * DD + q * 8;
#pragma unroll
      for (int kk = 0; kk < 4; ++kk) {
        us8_t u = *(const us8_t*)(X + kk * 32);
        h8_t o;
#pragma unroll
        for (int j = 0; j < 8; ++j) o[j] = (_Float16)bf2f(u[j]);
        a[kk] = o;
      }
    }
  } else {
    const _Float16* X = (const _Float16*)Xraw + (size_t)rr * DD + q * 8;
    const float* scp = bn;
    const float* shp = bn + 128;
    float p0 = bn[256], p1 = bn[257], p2 = bn[258], p3 = bn[259], p4 = bn[260];
#pragma unroll
    for (int kk = 0; kk < 4; ++kk) {
      h8_t x = *(const h8_t*)(X + kk * 32);
      int c0 = kk * 32 + q * 8;
      float scv[8], shv[8];
      *(float4*)scv = *(const float4*)(scp + c0);
      *(float4*)(scv + 4) = *(const float4*)(scp + c0 + 4);
      *(float4*)shv = *(const float4*)(shp + c0);
      *(float4*)(shv + 4) = *(const float4*)(shp + c0 + 4);
      h8_t o;
#pragma unroll
      for (int j = 0; j < 8; ++j) {
        float xn = fmaf((float)x[j], scv[j], shv[j]);
        xn = fminf(fmaxf(xn, -100.f), 100.f);
        float h = p4;
        h = fmaf(h, xn, p3);
        h = fmaf(h, xn, p2);
        h = fmaf(h, xn, p1);
        h = fmaf(h, xn, p0);
        o[j] = (_Float16)h;
      }
      a[kk] = o;
    }
  }
  f4_t acc[8] = {};
#pragma unroll
  for (int kk = 0; kk < 4; ++kk) {
#pragma unroll
    for (int t = 0; t < 8; ++t) {
      h8_t b = *(const h8_t*)(Wt + (((t * 4 + kk) * 64 + lane) << 3));
      acc[t] = __builtin_amdgcn_mfma_f32_16x16x32_f16(a[kk], b, acc[t], 0, 0, 0);
    }
  }
#pragma unroll
  for (int t = 0; t < 8; ++t) {
#pragma unroll
    for (int r = 0; r < 4; ++r) {
      int orow = r0 + q * 4 + r;
      if (orow < nrows)
        H[(size_t)orow * DD + t * 16 + m] = (_Float16)sat(acc[t][r]);
    }
  }
}

// ---------------- CSR aggregation (at the XCD-replication gather floor) --------
// 64-edge record chunk loaded coalesced (non-temporal: read-once stream),
// shuffle-broadcast per 4-edge group; 4 edges/iter (16 lanes x 16B gather);
// 4 nodes per wave seq, 16 per block. OUT stores non-temporal.
// Rationale: rec(12.8MB)+OUT(12.8MB) streams wash the 4MiB per-XCD L2 that
// holds the H gather working set (89% hit rate); nt keeps streams out of L2.
// FINAL=0: fp16 out.  FINAL=1: float32 out (d_out's dtype).
// STATS=1: per-lane reg accumulation, one LDS combine, 256 atomics per block.

template <int FINAL, int STATS>
__global__ __launch_bounds__(256) void k_agg(const _Float16* __restrict__ h,
                                             const int* __restrict__ offs,
                                             const int2* __restrict__ rec,
                                             const void* __restrict__ bias,
                                             void* __restrict__ outp, int n, int E,
                                             const int* __restrict__ flag,
                                             float* __restrict__ pb) {
  int f32m = *flag;
  int wid = threadIdx.x >> 6;
  int lane = threadIdx.x & 63;
  int sub = lane >> 4;   // which of 4 concurrent edges
  int fl = lane & 15;    // feature group (8 features, 16B)
  const u32x4* h128 = (const u32x4*)h;
  const u64* rec64 = (const u64*)rec;
  float ss[8] = {}, ss2[8] = {};
  float bv[8];
  {
    int c0 = fl << 3;
#pragma unroll
    for (int k = 0; k < 8; ++k) bv[k] = ldf(bias, c0 + k, f32m);
  }
#pragma unroll 1
  for (int t = 0; t < 4; ++t) {
    int node = (blockIdx.x << 4) + (wid << 2) + t;
    bool act = node < n;
    int beg = 0, end = 0;
    if (act) {
      beg = offs[node];
      end = offs[node + 1];
      if (beg < 0) beg = 0;
      if (end > E) end = E;
    }
    float a8[8] = {};
    for (int base = beg; base < end; base += 64) {
      int mm = end - base;
      if (mm > 64) mm = 64;
      int c = 0, wb = 0;
      if (lane < mm) {
        u64 rv = __builtin_nontemporal_load(&rec64[base + lane]);
        c = (int)(unsigned int)rv;          // low 32: col
        wb = (int)(unsigned int)(rv >> 32); // high 32: weight bits
      }
#pragma unroll 4
      for (int j = 0; j < mm; j += 4) {
        int idx = j + sub;  // <= 63 always; idx>=mm -> c=0,wb=0 (no-op fma)
        int cc = __shfl(c, idx);
        float ww = __int_as_float(__shfl(wb, idx));
        if ((unsigned)cc >= (unsigned)n) cc = 0;
        union { u32x4 u; h8_t f; } cv;
        cv.u = h128[(size_t)cc * 16 + fl];
#pragma unroll
        for (int k = 0; k < 8; ++k) a8[k] = fmaf((float)cv.f[k], ww, a8[k]);
      }
    }
#pragma unroll
    for (int k = 0; k < 8; ++k) a8[k] += __shfl_xor(a8[k], 16);
#pragma unroll
    for (int k = 0; k < 8; ++k) a8[k] += __shfl_xor(a8[k], 32);
    if (lane < 16 && act) {
      float o[8];
#pragma unroll
      for (int k = 0; k < 8; ++k) o[k] = sat(a8[k] + bv[k]);
      if (FINAL) {
        f32x4 v0 = {o[0], o[1], o[2], o[3]};
        f32x4 v1 = {o[4], o[5], o[6], o[7]};
        __builtin_nontemporal_store(v0, (f32x4*)outp + (size_t)node * 32 + fl * 2);
        __builtin_nontemporal_store(v1, (f32x4*)outp + (size_t)node * 32 + fl * 2 + 1);
      } else {
        union { u32x4 u; h8_t f; } cv;
#pragma unroll
        for (int k = 0; k < 8; ++k) cv.f[k] = (_Float16)o[k];
        __builtin_nontemporal_store(cv.u, (u32x4*)outp + (size_t)node * 16 + fl);
      }
      if (STATS) {
#pragma unroll
        for (int k = 0; k < 8; ++k) {
          ss[k] += o[k];
          ss2[k] = fmaf(o[k], o[k], ss2[k]);
        }
      }
    }
  }
  if (STATS) {
    __shared__ float sh[4][256];
    if (lane < 16) {
      int c0 = fl << 3;
#pragma unroll
      for (int k = 0; k < 8; ++k) {
        sh[wid][c0 + k] = ss[k];
        sh[wid][128 + c0 + k] = ss2[k];
      }
    }
    __syncthreads();
    int tid = threadIdx.x;
    float v = sh[0][tid] + sh[1][tid] + sh[2][tid] + sh[3][tid];
    float* dst = pb + ((blockIdx.x & 63) << 8);
    atomicAdd(&dst[tid], v);
  }
}

// ---------------- launch ----------------

extern "C" void kernel_launch(void* const* d_in, const int* in_sizes, int n_in,
                              void* d_out, int out_size, void* d_ws, size_t ws_size,
                              hipStream_t stream) {
  const void* nf = d_in[0];
  const int* row = (const int*)d_in[1];
  const int* col = (const int*)d_in[2];
  const void* ew = d_in[3];
  const void* W1 = d_in[4];
  const void* b1 = d_in[5];
  const void* W2 = d_in[6];
  const void* b2 = d_in[7];
  const void* W3 = d_in[8];
  const void* b3 = d_in[9];
  const void* g1 = d_in[10];
  const void* be1 = d_in[11];
  const void* g2 = d_in[12];
  const void* be2 = d_in[13];
  const void* coeffs = d_in[14];

  const int N = in_sizes[0] / DD;
  const int E = in_sizes[1];
  const int cstride = in_sizes[14] / 2;

  // ws ≈ 53MB (ws_size ≥ 66MB)
  char* p = (char*)d_ws;
  auto alloc = [&](size_t bytes) {
    char* r = p;
    p += (bytes + 255) & ~(size_t)255;
    return r;
  };
  int* flag = (int*)alloc(256);
  float* bn = (float*)alloc(2048);       // sc128 | sh128 | p5
  float* pb = (float*)alloc(65536);      // 64 x {sum[128] | sumsq[128]}
  int* bsum = (int*)alloc(4096);
  int* bcnt = (int*)alloc(1024);
  int* bbase = (int*)alloc(1088);
  int* bcur = (int*)alloc(1024);
  int p1b = (E + P1_T - 1) / P1_T;
  int* blkhist = (int*)alloc((size_t)p1b * 256 * 4);
  _Float16* Wt = (_Float16*)alloc(3 * 16384 * 2);
  _Float16* H16 = (_Float16*)alloc((size_t)N * DD * 2);
  int* deg = (int*)alloc((size_t)N * 4);
  int* offs = (int*)alloc((size_t)(N + 1) * 4);
  int* cursor = (int*)alloc((size_t)N * 4);
  int2* rec = (int2*)alloc((size_t)E * 8);
  u64* stage = (u64*)alloc((size_t)E * 8);

  _Float16* OUT = (_Float16*)d_out;  // fp16 agg scratch; k_agg<1> rewrites as f32

  int NB = (N + 511) >> 9;
  if (NB <= NBMAX) {
    // bucket-only CSR build: bhist(+detect) -> bscan -> p1(+cvt_w) -> p2n
    hipMemsetAsync(bcnt, 0, 1024, stream);
    k_bhist<<<p1b + 1, 256, 0, stream>>>(row, bcnt, E, N, (const unsigned int*)nf,
                                         flag, blkhist);
    k_bscan<<<1, 256, 0, stream>>>(bcnt, bbase, bcur, offs, NB, N);
    k_p1<<<p1b + 192, 256, 0, stream>>>(row, col, ew, bcur, stage, E, N, NB, flag,
                                        blkhist, W1, W2, W3, Wt, p1b);
    k_p2n<<<NB, 256, 0, stream>>>(bbase, stage, (u64*)rec, offs, N);
  } else {
    // fallback per-node chain
    int eb = (E + 255) / 256;
    hipMemsetAsync(deg, 0, (size_t)N * 4, stream);
    k_hist<<<eb + 1, 256, 0, stream>>>(row, deg, E, N, (const unsigned int*)nf, flag);
    int nb = (N + 1023) / 1024;
    k_scan1<<<nb, 256, 0, stream>>>(deg, bsum, N);
    k_scan2<<<1, 1024, 0, stream>>>(bsum, offs, nb, N);
    k_scan3<<<nb, 256, 0, stream>>>(deg, bsum, offs, cursor, N);
    k_fill<<<eb, 256, 0, stream>>>(row, col, ew, cursor, rec, E, N, flag);
    k_cvt_w<<<192, 256, 0, stream>>>(W1, W2, W3, Wt, flag);
  }

  int gemm_blocks = ((N + 15) / 16 + 3) / 4;
  int agg_blocks = (N + 15) / 16;
  float invN = 1.0f / (float)N;

  // layer 0: gemm(zero pb) -> agg(+stats) -> bnprep
  k_gemm<0><<<gemm_blocks, 256, 0, stream>>>(nf, Wt, H16, N, bn, flag, pb);
  k_agg<0, 1><<<agg_blocks, 256, 0, stream>>>(H16, offs, rec, b1, OUT, N, E, flag, pb);
  k_bnprep<<<1, 128, 0, stream>>>(pb, g1, be1, coeffs, 0, invN, bn, flag);

  // layer 1: gemm(zero pb) -> agg(+stats) -> bnprep
  k_gemm<1><<<gemm_blocks, 256, 0, stream>>>(OUT, Wt + 16384, H16, N, bn, flag, pb);
  k_agg<0, 1><<<agg_blocks, 256, 0, stream>>>(H16, offs, rec, b2, OUT, N, E, flag, pb);
  k_bnprep<<<1, 128, 0, stream>>>(pb, g2, be2, coeffs, cstride, invN, bn, flag);

  // layer 2: gemm -> agg (float32 out)
  k_gemm<1><<<gemm_blocks, 256, 0, stream>>>(OUT, Wt + 2 * 16384, H16, N, bn, flag, nullptr);
  k_agg<1, 0><<<agg_blocks, 256, 0, stream>>>(H16, offs, rec, b3, d_out, N, E, flag, pb);
}

// Round 12
// 486.771 us; speedup vs baseline: 1.1064x; 1.1064x over previous
//
#include <hip/hip_runtime.h>
#include <hip/hip_bf16.h>

#define DD 128

typedef _Float16 h8_t __attribute__((ext_vector_type(8)));
typedef _Float16 h4_t __attribute__((ext_vector_type(4)));
typedef unsigned short us8_t __attribute__((ext_vector_type(8)));
typedef float f4_t __attribute__((ext_vector_type(4)));
typedef unsigned long long u64;

__device__ inline float bf2f(unsigned short u) {
  union { unsigned int i; float f; } v;
  v.i = ((unsigned int)u) << 16;
  return v.f;
}

__device__ inline float sat(float v) {
  return fminf(fmaxf(v, -60000.f), 60000.f);
}

// dtype-adaptive scalar load: mode 1 = float32 array, mode 0 = bf16 array
__device__ inline float ldf(const void* p, int i, int f32m) {
  return f32m ? ((const float*)p)[i] : bf2f(((const unsigned short*)p)[i]);
}

#define P1_T 4096
#define NBMAX 256
#define P2_CAP 12288  // max records per bucket held in LDS (96KB); overflow -> direct

// shared weight-swizzle body:
// Wt[l][((t*4+kk)*64+lane)*8+j] = W_l[kk*32 + (lane>>4)*8 + j][t*16 + (lane&15)]
__device__ inline void cvt_w_body(const void* __restrict__ W1,
                                  const void* __restrict__ W2,
                                  const void* __restrict__ W3,
                                  _Float16* __restrict__ Wt, int f32m, int i) {
  if (i >= 3 * 16384) return;
  int l = i >> 14, o = i & 16383;
  int j = o & 7, lane = (o >> 3) & 63, kkt = o >> 9;
  int kk = kkt & 3, t = kkt >> 2;
  int k = kk * 32 + (lane >> 4) * 8 + j;
  int n = t * 16 + (lane & 15);
  const void* W = (l == 0) ? W1 : (l == 1 ? W2 : W3);
  Wt[i] = (_Float16)ldf(W, k * 128 + n, f32m);
}

// ---------------- bucket histogram (+ fused dtype-detect in last block) --------
// Persists each block's local histogram (blkhist) so k_p1 can skip its own
// phase-1 row pass entirely.

__global__ __launch_bounds__(256) void k_bhist(const int* __restrict__ row,
                                               int* __restrict__ bcnt, int E, int N,
                                               const unsigned int* __restrict__ nf,
                                               int* __restrict__ flag,
                                               int* __restrict__ blkhist) {
  if (blockIdx.x == gridDim.x - 1) {
    // dtype-detect block (flag=1 -> f32 inputs)
    __shared__ int cnt;
    if (threadIdx.x == 0) cnt = 0;
    __syncthreads();
    int bad = 0;
#pragma unroll
    for (int k = 0; k < 8; ++k) {
      unsigned int w = nf[threadIdx.x * 8 + k];
#pragma unroll
      for (int h = 0; h < 2; ++h) {
        unsigned short us = (h == 0) ? (unsigned short)(w & 0xFFFF)
                                     : (unsigned short)(w >> 16);
        float v = bf2f(us);
        float av = fabsf(v);
        if (!(av <= 1e5f) || (av != 0.f && av < 1e-30f)) bad++;
      }
    }
    atomicAdd(&cnt, bad);
    __syncthreads();
    if (threadIdx.x == 0) *flag = (cnt > 200) ? 1 : 0;
    return;
  }
  __shared__ int hist[NBMAX];
  int tid = threadIdx.x;
  hist[tid] = 0;
  __syncthreads();
  int e0 = blockIdx.x * P1_T;
#pragma unroll
  for (int k = 0; k < P1_T / 256; ++k) {
    int i = e0 + k * 256 + tid;
    if (i < E) {
      int r = row[i];
      if ((unsigned)r < (unsigned)N) atomicAdd(&hist[r >> 9], 1);
    }
  }
  __syncthreads();
  int c = hist[tid];
  blkhist[blockIdx.x * 256 + tid] = c;
  if (c) atomicAdd(&bcnt[tid], c);
}

// single block: scan NB bucket counts -> bucket bases + p1 cursors + offs[N]
__global__ __launch_bounds__(256) void k_bscan(const int* __restrict__ bcnt,
                                               int* __restrict__ bbase,
                                               int* __restrict__ bcur,
                                               int* __restrict__ offs,
                                               int NB, int N) {
  __shared__ int sh[NBMAX + 1];
  int tid = threadIdx.x;
  sh[tid] = (tid < NB) ? bcnt[tid] : 0;
  __syncthreads();
  if (tid == 0) {
    int run = 0;
    for (int i = 0; i < NB; ++i) {
      int t = sh[i];
      sh[i] = run;
      run += t;
    }
    sh[NB] = run;
    offs[N] = run;
  }
  __syncthreads();
  if (tid < NB) {
    bbase[tid] = sh[tid];
    bcur[tid] = sh[tid];
  }
  if (tid == 0) bbase[NB] = sh[NB];
}

// ---------------- bucketed fill pass 1 (+ fused weight swizzle blocks) --------
// Bucket = row>>9 (512 nodes). Requires N < 2^17 (=> NB <= 256, col fits 17 bits).
// Blocks >= p1b perform the weight swizzle (flag ready: detect ran in k_bhist).
// Phase-1 local histogram is read from blkhist (computed by k_bhist).

__global__ __launch_bounds__(256) void k_p1(const int* __restrict__ row,
                                            const int* __restrict__ col,
                                            const void* __restrict__ ew,
                                            int* __restrict__ bcur,
                                            u64* __restrict__ stage,
                                            int E, int N, int NB,
                                            const int* __restrict__ flag,
                                            const int* __restrict__ blkhist,
                                            const void* __restrict__ W1,
                                            const void* __restrict__ W2,
                                            const void* __restrict__ W3,
                                            _Float16* __restrict__ Wt, int p1b) {
  int f32m = *flag;
  if (blockIdx.x >= p1b) {
    cvt_w_body(W1, W2, W3, Wt, f32m, (blockIdx.x - p1b) * 256 + threadIdx.x);
    return;
  }
  __shared__ int hist[NBMAX];
  __shared__ int basep[NBMAX];
  int tid = threadIdx.x;
  int e0 = blockIdx.x * P1_T;
  if (tid < NB) {
    int c = blkhist[blockIdx.x * 256 + tid];
    basep[tid] = c ? atomicAdd(&bcur[tid], c) : 0;
    hist[tid] = 0;
  }
  __syncthreads();
#pragma unroll
  for (int k = 0; k < P1_T / 256; ++k) {
    int i = e0 + k * 256 + tid;
    if (i < E) {
      int r = row[i];
      if ((unsigned)r < (unsigned)N) {
        int b = r >> 9;
        int loc = atomicAdd(&hist[b], 1);
        int pos = basep[b] + loc;
        int c = col[i];
        if ((unsigned)c >= (unsigned)N) c = 0;
        unsigned int wb = __float_as_uint(ldf(ew, i, f32m));
        u64 pk = ((u64)wb << 32) | (unsigned int)(c | ((r & 511) << 17));
        stage[pos] = pk;
      }
    }
  }
}

// ---------------- pass 2: per-node offsets + record placement ----------------

__global__ __launch_bounds__(256) void k_p2n(const int* __restrict__ bbase,
                                             const u64* __restrict__ stage,
                                             u64* __restrict__ rec,
                                             int* __restrict__ offs, int N) {
  __shared__ int lcnt[512];
  __shared__ int lex[512];
  __shared__ int wsum[4];
  __shared__ u64 recbuf[P2_CAP];
  int b = blockIdx.x;
  int base = b << 9;
  int nend = base + 512;
  if (nend > N) nend = N;
  int nn = nend - base;
  int recbase = bbase[b];
  int cnt = bbase[b + 1] - recbase;
  int tid = threadIdx.x;
  lcnt[tid] = 0;
  lcnt[tid + 256] = 0;
  __syncthreads();
  for (int j = tid; j < cnt; j += 256) {
    unsigned int lo = (unsigned int)stage[recbase + j];
    atomicAdd(&lcnt[(lo >> 17) & 511], 1);
  }
  __syncthreads();
  // exclusive scan of 512 counters (2 per thread, wave scan + wave-sum combine)
  int v0 = lcnt[2 * tid], v1 = lcnt[2 * tid + 1];
  int s = v0 + v1;
  int sc = s;
  int lane = tid & 63, w = tid >> 6;
#pragma unroll
  for (int d = 1; d < 64; d <<= 1) {
    int t = __shfl_up(sc, d, 64);
    if (lane >= d) sc += t;
  }
  if (lane == 63) wsum[w] = sc;
  __syncthreads();
  int wbase = 0;
  for (int x = 0; x < w; ++x) wbase += wsum[x];
  int run = wbase + (sc - s);
  lex[2 * tid] = run;
  lex[2 * tid + 1] = run + v0;
  __syncthreads();
  for (int v = tid; v < nn; v += 256) offs[base + v] = recbase + lex[v];
  // reuse lcnt as placement cursors
  lcnt[tid] = lex[tid];
  lcnt[tid + 256] = lex[tid + 256];
  __syncthreads();
  for (int j = tid; j < cnt; j += 256) {
    u64 pk = stage[recbase + j];
    unsigned int lo = (unsigned int)pk;
    unsigned int wb = (unsigned int)(pk >> 32);
    int c = lo & 0x1FFFF;
    int rloc = (lo >> 17) & 511;
    int pos = atomicAdd(&lcnt[rloc], 1);
    u64 out = ((u64)wb << 32) | (unsigned int)c;  // int2{col, wbits} little-endian
    if (pos < P2_CAP) recbuf[pos] = out;
    else rec[recbase + pos] = out;
  }
  __syncthreads();
  int m = cnt < P2_CAP ? cnt : P2_CAP;
  for (int j = tid; j < m; j += 256) rec[recbase + j] = recbuf[j];
}

// ---------------- fallback chain (N >= 2^17 only) ----------------

__global__ __launch_bounds__(256) void k_hist(const int* __restrict__ row,
                                              int* __restrict__ deg, int E, int N,
                                              const unsigned int* __restrict__ nf,
                                              int* __restrict__ flag) {
  if (blockIdx.x == gridDim.x - 1) {
    __shared__ int cnt;
    if (threadIdx.x == 0) cnt = 0;
    __syncthreads();
    int bad = 0;
#pragma unroll
    for (int k = 0; k < 8; ++k) {
      unsigned int w = nf[threadIdx.x * 8 + k];
#pragma unroll
      for (int h = 0; h < 2; ++h) {
        unsigned short us = (h == 0) ? (unsigned short)(w & 0xFFFF)
                                     : (unsigned short)(w >> 16);
        float v = bf2f(us);
        float av = fabsf(v);
        if (!(av <= 1e5f) || (av != 0.f && av < 1e-30f)) bad++;
      }
    }
    atomicAdd(&cnt, bad);
    __syncthreads();
    if (threadIdx.x == 0) *flag = (cnt > 200) ? 1 : 0;
    return;
  }
  int i = blockIdx.x * 256 + threadIdx.x;
  if (i < E) {
    int r = row[i];
    if ((unsigned)r < (unsigned)N) atomicAdd(&deg[r], 1);
  }
}

__global__ __launch_bounds__(256) void k_scan1(const int* __restrict__ deg,
                                               int* __restrict__ bsum, int n) {
  int i0 = blockIdx.x * 1024 + threadIdx.x * 4;
  int s = 0;
#pragma unroll
  for (int k = 0; k < 4; ++k) {
    int i = i0 + k;
    if (i < n) s += deg[i];
  }
#pragma unroll
  for (int d = 1; d < 64; d <<= 1) s += __shfl_xor(s, d, 64);
  __shared__ int ws[4];
  int lane = threadIdx.x & 63, w = threadIdx.x >> 6;
  if (lane == 0) ws[w] = s;
  __syncthreads();
  if (threadIdx.x == 0) bsum[blockIdx.x] = ws[0] + ws[1] + ws[2] + ws[3];
}

__global__ __launch_bounds__(1024) void k_scan2(int* __restrict__ bsum,
                                                int* __restrict__ offs,
                                                int nb, int n) {
  __shared__ int sh[1024];
  int tid = threadIdx.x;
  sh[tid] = (tid < nb) ? bsum[tid] : 0;
  __syncthreads();
  if (tid == 0) {
    int run = 0;
    for (int i = 0; i < nb; ++i) {
      int t = sh[i];
      sh[i] = run;
      run += t;
    }
    offs[n] = run;
  }
  __syncthreads();
  if (tid < nb) bsum[tid] = sh[tid];
}

__global__ __launch_bounds__(256) void k_scan3(const int* __restrict__ deg,
                                               const int* __restrict__ bsum,
                                               int* __restrict__ offs,
                                               int* __restrict__ cursor, int n) {
  int tid = threadIdx.x, lane = tid & 63, w = tid >> 6;
  int i0 = blockIdx.x * 1024 + tid * 4;
  int v0 = 0, v1 = 0, v2 = 0, v3 = 0;
  if (i0 + 3 < n) {
    v0 = deg[i0]; v1 = deg[i0 + 1]; v2 = deg[i0 + 2]; v3 = deg[i0 + 3];
  } else {
    if (i0 < n) v0 = deg[i0];
    if (i0 + 1 < n) v1 = deg[i0 + 1];
    if (i0 + 2 < n) v2 = deg[i0 + 2];
  }
  int s = v0 + v1 + v2 + v3;
  int sc = s;
#pragma unroll
  for (int d = 1; d < 64; d <<= 1) {
    int t = __shfl_up(sc, d, 64);
    if (lane >= d) sc += t;
  }
  __shared__ int ws[4];
  if (lane == 63) ws[w] = sc;
  __syncthreads();
  int wbase = 0;
  for (int x = 0; x < w; ++x) wbase += ws[x];
  int run = bsum[blockIdx.x] + wbase + (sc - s);
  if (i0 < n)     { offs[i0] = run;     cursor[i0] = run;     run += v0; }
  if (i0 + 1 < n) { offs[i0 + 1] = run; cursor[i0 + 1] = run; run += v1; }
  if (i0 + 2 < n) { offs[i0 + 2] = run; cursor[i0 + 2] = run; run += v2; }
  if (i0 + 3 < n) { offs[i0 + 3] = run; cursor[i0 + 3] = run; }
}

__global__ __launch_bounds__(256) void k_fill(const int* __restrict__ row,
                                              const int* __restrict__ col,
                                              const void* __restrict__ ew,
                                              int* __restrict__ cursor,
                                              int2* __restrict__ rec, int E, int N,
                                              const int* __restrict__ flag) {
  int f32m = *flag;
  int i = blockIdx.x * 256 + threadIdx.x;
  if (i >= E) return;
  int r = row[i];
  if ((unsigned)r >= (unsigned)N) return;
  int p = atomicAdd(&cursor[r], 1);
  if ((unsigned)p >= (unsigned)E) return;
  int c = col[i];
  if ((unsigned)c >= (unsigned)N) c = 0;
  rec[p] = make_int2(c, __float_as_int(ldf(ew, i, f32m)));
}

__global__ __launch_bounds__(256) void k_cvt_w(const void* __restrict__ W1,
                                               const void* __restrict__ W2,
                                               const void* __restrict__ W3,
                                               _Float16* __restrict__ Wt,
                                               const int* __restrict__ flag) {
  cvt_w_body(W1, W2, W3, Wt, *flag, blockIdx.x * 256 + threadIdx.x);
}

// ---------------- BN prep: reduce 64 stat partials -> scale/shift + coeffs ----
// pb layout: [64][256] = {sum[128] | sumsq[128]} per slot
// bn[0..127]=sc, bn[128..255]=sh, bn[256..260]=p0..p4
// NOTE (R9 lesson): do NOT fuse this into k_agg via grid-counter+__threadfence —
// device-scope fences per block flush L2 across XCDs and collapsed agg 82->711us.

__global__ __launch_bounds__(128) void k_bnprep(const float* __restrict__ pb,
                                                const void* __restrict__ gamma,
                                                const void* __restrict__ beta,
                                                const void* __restrict__ coeffs,
                                                int coff, float invN,
                                                float* __restrict__ bn,
                                                const int* __restrict__ flag) {
  int f32m = *flag;
  int c = threadIdx.x;
  float s = 0.f, s2 = 0.f;
#pragma unroll 8
  for (int p = 0; p < 64; ++p) {
    s += pb[p * 256 + c];
    s2 += pb[p * 256 + 128 + c];
  }
  float mn = s * invN;
  float var = fmaf(-mn, mn, s2 * invN);
  var = fmaxf(var, 0.0f);
  float inv = rsqrtf(var + 1e-5f);
  float g = ldf(gamma, c, f32m);
  float scv = g * inv;
  bn[c] = scv;
  bn[128 + c] = ldf(beta, c, f32m) - mn * scv;
  if (c < 5) bn[256 + c] = ldf(coeffs, coff + c, f32m);
}

// ---------------- GEMM (MFMA): H = act(X) @ W ----------------
// MODE 0: X = raw input (f32 or bf16 per flag), no activation (layer 0)
// MODE 1: X = fp16 agg output; apply BN (sc,sh) + 4th-order Horner inline
// A frag: m=lane&15, k=(lane>>4)*8+j.  B pre-swizzled.  C/D: col=m, row=q*4+reg.
// pbz != null: blocks 0..63 zero the stats partial buffer (replaces memset).

template <int MODE>
__global__ __launch_bounds__(256) void k_gemm(const void* __restrict__ Xraw,
                                              const _Float16* __restrict__ Wt,
                                              _Float16* __restrict__ H, int nrows,
                                              const float* __restrict__ bn,
                                              const int* __restrict__ flag,
                                              float* __restrict__ pbz) {
  if (pbz != nullptr && blockIdx.x < 64)
    pbz[(blockIdx.x << 8) + threadIdx.x] = 0.f;
  int gw = (blockIdx.x * 256 + threadIdx.x) >> 6;
  int lane = threadIdx.x & 63;
  int r0 = gw << 4;
  if (r0 >= nrows) return;
  int m = lane & 15, q = lane >> 4;
  int rr = r0 + m;
  if (rr >= nrows) rr = nrows - 1;
  h8_t a[4];
  if (MODE == 0) {
    int f32m = *flag;
    if (f32m) {
      const float* X = (const float*)Xraw + (size_t)rr * DD + q * 8;
#pragma unroll
      for (int kk = 0; kk < 4; ++kk) {
        float4 u0 = *(const float4*)(X + kk * 32);
        float4 u1 = *(const float4*)(X + kk * 32 + 4);
        a[kk] = h8_t{(_Float16)u0.x, (_Float16)u0.y, (_Float16)u0.z, (_Float16)u0.w,
                     (_Float16)u1.x, (_Float16)u1.y, (_Float16)u1.z, (_Float16)u1.w};
      }
    } else {
      const unsigned short* X = (const unsigned short*)Xraw + (size_t)rr * DD + q * 8;
#pragma unroll
      for (int kk = 0; kk < 4; ++kk) {
        us8_t u = *(const us8_t*)(X + kk * 32);
        h8_t o;
#pragma unroll
        for (int j = 0; j < 8; ++j) o[j] = (_Float16)bf2f(u[j]);
        a[kk] = o;
      }
    }
  } else {
    const _Float16* X = (const _Float16*)Xraw + (size_t)rr * DD + q * 8;
    const float* scp = bn;
    const float* shp = bn + 128;
    float p0 = bn[256], p1 = bn[257], p2 = bn[258], p3 = bn[259], p4 = bn[260];
#pragma unroll
    for (int kk = 0; kk < 4; ++kk) {
      h8_t x = *(const h8_t*)(X + kk * 32);
      int c0 = kk * 32 + q * 8;
      float scv[8], shv[8];
      *(float4*)scv = *(const float4*)(scp + c0);
      *(float4*)(scv + 4) = *(const float4*)(scp + c0 + 4);
      *(float4*)shv = *(const float4*)(shp + c0);
      *(float4*)(shv + 4) = *(const float4*)(shp + c0 + 4);
      h8_t o;
#pragma unroll
      for (int j = 0; j < 8; ++j) {
        float xn = fmaf((float)x[j], scv[j], shv[j]);
        xn = fminf(fmaxf(xn, -100.f), 100.f);
        float h = p4;
        h = fmaf(h, xn, p3);
        h = fmaf(h, xn, p2);
        h = fmaf(h, xn, p1);
        h = fmaf(h, xn, p0);
        o[j] = (_Float16)h;
      }
      a[kk] = o;
    }
  }
  f4_t acc[8] = {};
#pragma unroll
  for (int kk = 0; kk < 4; ++kk) {
#pragma unroll
    for (int t = 0; t < 8; ++t) {
      h8_t b = *(const h8_t*)(Wt + (((t * 4 + kk) * 64 + lane) << 3));
      acc[t] = __builtin_amdgcn_mfma_f32_16x16x32_f16(a[kk], b, acc[t], 0, 0, 0);
    }
  }
#pragma unroll
  for (int t = 0; t < 8; ++t) {
#pragma unroll
    for (int r = 0; r < 4; ++r) {
      int orow = r0 + q * 4 + r;
      if (orow < nrows)
        H[(size_t)orow * DD + t * 16 + m] = (_Float16)sat(acc[t][r]);
    }
  }
}

// ---------------- CSR aggregation (at the XCD-replication gather floor) --------
// 64-edge record chunk loaded coalesced, shuffle-broadcast per 4-edge group;
// 4 edges/iter (16 lanes x 16B gather each); 4 nodes per wave seq, 16 per block.
// FINAL=0: fp16 out.  FINAL=1: float32 out (d_out's dtype).
// STATS=1: per-lane reg accumulation, one LDS combine, 256 atomics per block.
// NOTE (R11 lesson): __builtin_nontemporal_* on rec/OUT REGRESSED (-4us/dispatch,
// FETCH flat) — TCC default policy already optimal; 182MB fetch is compulsory
// cross-XCD replication of the 25.6MB H working set, not pollution.

template <int FINAL, int STATS>
__global__ __launch_bounds__(256) void k_agg(const _Float16* __restrict__ h,
                                             const int* __restrict__ offs,
                                             const int2* __restrict__ rec,
                                             const void* __restrict__ bias,
                                             void* __restrict__ outp, int n, int E,
                                             const int* __restrict__ flag,
                                             float* __restrict__ pb) {
  int f32m = *flag;
  int wid = threadIdx.x >> 6;
  int lane = threadIdx.x & 63;
  int sub = lane >> 4;   // which of 4 concurrent edges
  int fl = lane & 15;    // feature group (8 features, 16B)
  const uint4* h128 = (const uint4*)h;
  float ss[8] = {}, ss2[8] = {};
  float bv[8];
  {
    int c0 = fl << 3;
#pragma unroll
    for (int k = 0; k < 8; ++k) bv[k] = ldf(bias, c0 + k, f32m);
  }
#pragma unroll 1
  for (int t = 0; t < 4; ++t) {
    int node = (blockIdx.x << 4) + (wid << 2) + t;
    bool act = node < n;
    int beg = 0, end = 0;
    if (act) {
      beg = offs[node];
      end = offs[node + 1];
      if (beg < 0) beg = 0;
      if (end > E) end = E;
    }
    float a8[8] = {};
    for (int base = beg; base < end; base += 64) {
      int mm = end - base;
      if (mm > 64) mm = 64;
      int c = 0, wb = 0;
      if (lane < mm) {
        int2 r = rec[base + lane];
        c = r.x;
        wb = r.y;
      }
#pragma unroll 4
      for (int j = 0; j < mm; j += 4) {
        int idx = j + sub;  // <= 63 always; idx>=mm -> c=0,wb=0 (no-op fma)
        int cc = __shfl(c, idx);
        float ww = __int_as_float(__shfl(wb, idx));
        if ((unsigned)cc >= (unsigned)n) cc = 0;
        union { uint4 u; h8_t f; } cv;
        cv.u = h128[(size_t)cc * 16 + fl];
#pragma unroll
        for (int k = 0; k < 8; ++k) a8[k] = fmaf((float)cv.f[k], ww, a8[k]);
      }
    }
#pragma unroll
    for (int k = 0; k < 8; ++k) a8[k] += __shfl_xor(a8[k], 16);
#pragma unroll
    for (int k = 0; k < 8; ++k) a8[k] += __shfl_xor(a8[k], 32);
    if (lane < 16 && act) {
      float o[8];
#pragma unroll
      for (int k = 0; k < 8; ++k) o[k] = sat(a8[k] + bv[k]);
      if (FINAL) {
        float4 v0 = make_float4(o[0], o[1], o[2], o[3]);
        float4 v1 = make_float4(o[4], o[5], o[6], o[7]);
        ((float4*)outp)[(size_t)node * 32 + fl * 2] = v0;
        ((float4*)outp)[(size_t)node * 32 + fl * 2 + 1] = v1;
      } else {
        union { uint4 u; h8_t f; } cv;
#pragma unroll
        for (int k = 0; k < 8; ++k) cv.f[k] = (_Float16)o[k];
        ((uint4*)outp)[(size_t)node * 16 + fl] = cv.u;
      }
      if (STATS) {
#pragma unroll
        for (int k = 0; k < 8; ++k) {
          ss[k] += o[k];
          ss2[k] = fmaf(o[k], o[k], ss2[k]);
        }
      }
    }
  }
  if (STATS) {
    __shared__ float sh[4][256];
    if (lane < 16) {
      int c0 = fl << 3;
#pragma unroll
      for (int k = 0; k < 8; ++k) {
        sh[wid][c0 + k] = ss[k];
        sh[wid][128 + c0 + k] = ss2[k];
      }
    }
    __syncthreads();
    int tid = threadIdx.x;
    float v = sh[0][tid] + sh[1][tid] + sh[2][tid] + sh[3][tid];
    float* dst = pb + ((blockIdx.x & 63) << 8);
    atomicAdd(&dst[tid], v);
  }
}

// ---------------- launch ----------------

extern "C" void kernel_launch(void* const* d_in, const int* in_sizes, int n_in,
                              void* d_out, int out_size, void* d_ws, size_t ws_size,
                              hipStream_t stream) {
  const void* nf = d_in[0];
  const int* row = (const int*)d_in[1];
  const int* col = (const int*)d_in[2];
  const void* ew = d_in[3];
  const void* W1 = d_in[4];
  const void* b1 = d_in[5];
  const void* W2 = d_in[6];
  const void* b2 = d_in[7];
  const void* W3 = d_in[8];
  const void* b3 = d_in[9];
  const void* g1 = d_in[10];
  const void* be1 = d_in[11];
  const void* g2 = d_in[12];
  const void* be2 = d_in[13];
  const void* coeffs = d_in[14];

  const int N = in_sizes[0] / DD;
  const int E = in_sizes[1];
  const int cstride = in_sizes[14] / 2;

  // ws ≈ 53MB (ws_size ≥ 66MB)
  char* p = (char*)d_ws;
  auto alloc = [&](size_t bytes) {
    char* r = p;
    p += (bytes + 255) & ~(size_t)255;
    return r;
  };
  int* flag = (int*)alloc(256);
  float* bn = (float*)alloc(2048);       // sc128 | sh128 | p5
  float* pb = (float*)alloc(65536);      // 64 x {sum[128] | sumsq[128]}
  int* bsum = (int*)alloc(4096);
  int* bcnt = (int*)alloc(1024);
  int* bbase = (int*)alloc(1088);
  int* bcur = (int*)alloc(1024);
  int p1b = (E + P1_T - 1) / P1_T;
  int* blkhist = (int*)alloc((size_t)p1b * 256 * 4);
  _Float16* Wt = (_Float16*)alloc(3 * 16384 * 2);
  _Float16* H16 = (_Float16*)alloc((size_t)N * DD * 2);
  int* deg = (int*)alloc((size_t)N * 4);
  int* offs = (int*)alloc((size_t)(N + 1) * 4);
  int* cursor = (int*)alloc((size_t)N * 4);
  int2* rec = (int2*)alloc((size_t)E * 8);
  u64* stage = (u64*)alloc((size_t)E * 8);

  _Float16* OUT = (_Float16*)d_out;  // fp16 agg scratch; k_agg<1> rewrites as f32

  int NB = (N + 511) >> 9;
  if (NB <= NBMAX) {
    // bucket-only CSR build: bhist(+detect) -> bscan -> p1(+cvt_w) -> p2n
    hipMemsetAsync(bcnt, 0, 1024, stream);
    k_bhist<<<p1b + 1, 256, 0, stream>>>(row, bcnt, E, N, (const unsigned int*)nf,
                                         flag, blkhist);
    k_bscan<<<1, 256, 0, stream>>>(bcnt, bbase, bcur, offs, NB, N);
    k_p1<<<p1b + 192, 256, 0, stream>>>(row, col, ew, bcur, stage, E, N, NB, flag,
                                        blkhist, W1, W2, W3, Wt, p1b);
    k_p2n<<<NB, 256, 0, stream>>>(bbase, stage, (u64*)rec, offs, N);
  } else {
    // fallback per-node chain
    int eb = (E + 255) / 256;
    hipMemsetAsync(deg, 0, (size_t)N * 4, stream);
    k_hist<<<eb + 1, 256, 0, stream>>>(row, deg, E, N, (const unsigned int*)nf, flag);
    int nb = (N + 1023) / 1024;
    k_scan1<<<nb, 256, 0, stream>>>(deg, bsum, N);
    k_scan2<<<1, 1024, 0, stream>>>(bsum, offs, nb, N);
    k_scan3<<<nb, 256, 0, stream>>>(deg, bsum, offs, cursor, N);
    k_fill<<<eb, 256, 0, stream>>>(row, col, ew, cursor, rec, E, N, flag);
    k_cvt_w<<<192, 256, 0, stream>>>(W1, W2, W3, Wt, flag);
  }

  int gemm_blocks = ((N + 15) / 16 + 3) / 4;
  int agg_blocks = (N + 15) / 16;
  float invN = 1.0f / (float)N;

  // layer 0: gemm(zero pb) -> agg(+stats) -> bnprep
  k_gemm<0><<<gemm_blocks, 256, 0, stream>>>(nf, Wt, H16, N, bn, flag, pb);
  k_agg<0, 1><<<agg_blocks, 256, 0, stream>>>(H16, offs, rec, b1, OUT, N, E, flag, pb);
  k_bnprep<<<1, 128, 0, stream>>>(pb, g1, be1, coeffs, 0, invN, bn, flag);

  // layer 1: gemm(zero pb) -> agg(+stats) -> bnprep
  k_gemm<1><<<gemm_blocks, 256, 0, stream>>>(OUT, Wt + 16384, H16, N, bn, flag, pb);
  k_agg<0, 1><<<agg_blocks, 256, 0, stream>>>(H16, offs, rec, b2, OUT, N, E, flag, pb);
  k_bnprep<<<1, 128, 0, stream>>>(pb, g2, be2, coeffs, cstride, invN, bn, flag);

  // layer 2: gemm -> agg (float32 out)
  k_gemm<1><<<gemm_blocks, 256, 0, stream>>>(OUT, Wt + 2 * 16384, H16, N, bn, flag, nullptr);
  k_agg<1, 0><<<agg_blocks, 256, 0, stream>>>(H16, offs, rec, b3, d_out, N, E, flag, pb);
}